// Round 1
// baseline (4997.877 us; speedup 1.0000x reference)
//
#include <hip/hip_runtime.h>
#include <math.h>

#define HD    128      // hidden
#define GATES 512      // 4H
#define BB    64       // batch
#define CL    512      // context len
#define QL    64       // query len

__device__ __forceinline__ float sigmoidf_(float x) { return 1.f / (1.f + expf(-x)); }

// ---------------------------------------------------------------------------
// GEMM: C[n][j] = sum_k A[row(n)][k] * W[j][k] + bias[j]
// A row-major (lda=K), optionally gathered through gidx (emb lookup).
// W row-major (512, K). Output C (N,512), dir via blockIdx.z.
// Tiles: BM=128, BN=128, BK=32, 256 threads, 8x8 per thread.
// ---------------------------------------------------------------------------
__global__ __launch_bounds__(256)
void gemm_xg(const float* __restrict__ A, const int* __restrict__ gidx,
             const float* __restrict__ Wih, const float* __restrict__ bias,
             float* __restrict__ C, int N, int K)
{
    const int dir = blockIdx.z;
    const float* W  = Wih  + (size_t)dir * GATES * K;
    const float* bi = bias + (size_t)dir * GATES;
    float* Cd = C + (size_t)dir * N * GATES;

    const int m0  = blockIdx.x * 128;
    const int n0  = blockIdx.y * 128;
    const int tid = threadIdx.x;

    __shared__ __align__(16) float as_[32][132];
    __shared__ __align__(16) float bs_[32][132];

    float acc[8][8];
#pragma unroll
    for (int i = 0; i < 8; ++i)
#pragma unroll
        for (int j = 0; j < 8; ++j) acc[i][j] = 0.f;

    const int lr = tid >> 3;        // 0..31 row within tile
    const int lc = (tid & 7) * 4;   // 0,4,..28 k-offset
    const int ty = tid >> 4;        // 0..15 -> m block
    const int tx = tid & 15;        // 0..15 -> n block

    // hoist gather indices (constant across k-loop)
    size_t arow[4];
#pragma unroll
    for (int it = 0; it < 4; ++it) {
        int row = m0 + lr + it * 32;
        arow[it] = (size_t)(gidx ? gidx[row] : row);
    }

    for (int k0 = 0; k0 < K; k0 += 32) {
        // stage A tile (transposed into [k][m])
#pragma unroll
        for (int it = 0; it < 4; ++it) {
            int m = lr + it * 32;
            const float* ap = A + arow[it] * K + k0 + lc;
            float4 v;
            int kk = k0 + lc;
            if (kk + 3 < K) {
                v = *(const float4*)ap;
            } else {
                v.x = (kk     < K) ? ap[0] : 0.f;
                v.y = (kk + 1 < K) ? ap[1] : 0.f;
                v.z = (kk + 2 < K) ? ap[2] : 0.f;
                v.w = (kk + 3 < K) ? ap[3] : 0.f;
            }
            as_[lc    ][m] = v.x;
            as_[lc + 1][m] = v.y;
            as_[lc + 2][m] = v.z;
            as_[lc + 3][m] = v.w;
        }
        // stage W tile
#pragma unroll
        for (int it = 0; it < 4; ++it) {
            int n = lr + it * 32;
            const float* wp = W + (size_t)(n0 + n) * K + k0 + lc;
            float4 v;
            int kk = k0 + lc;
            if (kk + 3 < K) {
                v = *(const float4*)wp;
            } else {
                v.x = (kk     < K) ? wp[0] : 0.f;
                v.y = (kk + 1 < K) ? wp[1] : 0.f;
                v.z = (kk + 2 < K) ? wp[2] : 0.f;
                v.w = (kk + 3 < K) ? wp[3] : 0.f;
            }
            bs_[lc    ][n] = v.x;
            bs_[lc + 1][n] = v.y;
            bs_[lc + 2][n] = v.z;
            bs_[lc + 3][n] = v.w;
        }
        __syncthreads();
#pragma unroll
        for (int k = 0; k < 32; ++k) {
            float4 a0 = *(const float4*)&as_[k][ty * 8];
            float4 a1 = *(const float4*)&as_[k][ty * 8 + 4];
            float4 b0 = *(const float4*)&bs_[k][tx * 8];
            float4 b1 = *(const float4*)&bs_[k][tx * 8 + 4];
            float am[8] = {a0.x, a0.y, a0.z, a0.w, a1.x, a1.y, a1.z, a1.w};
            float bn[8] = {b0.x, b0.y, b0.z, b0.w, b1.x, b1.y, b1.z, b1.w};
#pragma unroll
            for (int i = 0; i < 8; ++i)
#pragma unroll
                for (int j = 0; j < 8; ++j) acc[i][j] += am[i] * bn[j];
        }
        __syncthreads();
    }
    // epilogue: bias + store
#pragma unroll
    for (int i = 0; i < 8; ++i) {
        int row = m0 + ty * 8 + i;
        float* cp = Cd + (size_t)row * GATES + n0 + tx * 8;
#pragma unroll
        for (int j = 0; j < 8; j += 4) {
            float4 v;
            v.x = acc[i][j]     + bi[n0 + tx * 8 + j];
            v.y = acc[i][j + 1] + bi[n0 + tx * 8 + j + 1];
            v.z = acc[i][j + 2] + bi[n0 + tx * 8 + j + 2];
            v.w = acc[i][j + 3] + bi[n0 + tx * 8 + j + 3];
            *(float4*)(cp + j) = v;
        }
    }
}

// ---------------------------------------------------------------------------
// LSTM scan: one block per (batch, direction). 512 threads; thread j owns
// gate row j (Whh[j][0..127] in 128 VGPRs). h broadcast via LDS.
// xg layout (2,B,T,512); hout layout (B,T,256) with dir half offset.
// ---------------------------------------------------------------------------
__global__ __launch_bounds__(512)
void lstm_scan(const float* __restrict__ xg, const float* __restrict__ Whh,
               float* __restrict__ hout, int T)
{
    const int b   = blockIdx.x;
    const int dir = blockIdx.y;
    const int j   = threadIdx.x;

    const float* xgd = xg + (size_t)dir * BB * T * GATES;
    const float* wr  = Whh + ((size_t)dir * GATES + j) * HD;

    float4 w[32];
#pragma unroll
    for (int kk = 0; kk < 32; ++kk) w[kk] = *(const float4*)(wr + kk * 4);

    __shared__ __align__(16) float hs[HD];
    __shared__ float gs[GATES];

    if (j < HD) hs[j] = 0.f;
    float c = 0.f;
    __syncthreads();

    int t = dir ? (T - 1) : 0;
    const int dt = dir ? -1 : 1;

    float xcur = xgd[((size_t)b * T + t) * GATES + j];

    for (int step = 0; step < T; ++step) {
        int tn = t + dt;
        float xnext = (step + 1 < T) ? xgd[((size_t)b * T + tn) * GATES + j] : 0.f;

        float acc = xcur;
#pragma unroll
        for (int kk = 0; kk < 32; ++kk) {
            float4 h4 = *(const float4*)&hs[kk * 4];
            acc += w[kk].x * h4.x + w[kk].y * h4.y + w[kk].z * h4.z + w[kk].w * h4.w;
        }
        gs[j] = acc;
        __syncthreads();
        if (j < HD) {
            float ig = sigmoidf_(gs[j]);
            float fg = sigmoidf_(gs[HD + j]);
            float gg = tanhf(gs[2 * HD + j]);
            float og = sigmoidf_(gs[3 * HD + j]);
            c = fg * c + ig * gg;
            float h = og * tanhf(c);
            hs[j] = h;
            hout[((size_t)b * T + t) * 256 + dir * HD + j] = h;
        }
        __syncthreads();
        xcur = xnext;
        t = tn;
    }
}

// ---------------------------------------------------------------------------
// rowdot: out[n] = sum_d X[n][d] * w[d]   (one wave per row)
// ---------------------------------------------------------------------------
__global__ void rowdot(const float* __restrict__ X, const float* __restrict__ w,
                       float* __restrict__ out, int N, int D)
{
    int gw   = (int)((blockIdx.x * blockDim.x + threadIdx.x) >> 6);
    int lane = threadIdx.x & 63;
    if (gw >= N) return;
    const float* xp = X + (size_t)gw * D;
    float s = 0.f;
    for (int d = lane; d < D; d += 64) s += xp[d] * w[d];
#pragma unroll
    for (int off = 32; off; off >>= 1) s += __shfl_down(s, off);
    if (lane == 0) out[gw] = s;
}

// ---------------------------------------------------------------------------
// attention similarity: s[b,c,q] = cw[b,c] + qw[b,q] + sum_d co*wcq*qo + att_b
// grid (B, CL/64), 256 threads, 4c x 4q per thread.
// ---------------------------------------------------------------------------
__global__ __launch_bounds__(256)
void att_s(const float* __restrict__ co, const float* __restrict__ qo,
           const float* __restrict__ cw, const float* __restrict__ qw,
           const float* __restrict__ wcq, const float* __restrict__ attb,
           float* __restrict__ s)
{
    int b  = blockIdx.x;
    int c0 = blockIdx.y * 64;
    int tid = threadIdx.x;
    int tq = tid & 15, trc = tid >> 4;
    int cbase = c0 + trc * 4, qbase = tq * 4;

    float acc[4][4];
#pragma unroll
    for (int i = 0; i < 4; ++i)
#pragma unroll
        for (int j = 0; j < 4; ++j) acc[i][j] = 0.f;

    for (int d = 0; d < 256; d += 4) {
        float4 wv = *(const float4*)&wcq[d];
        float4 cv[4], qv[4];
#pragma unroll
        for (int i = 0; i < 4; ++i) {
            float4 v = *(const float4*)&co[((size_t)b * CL + cbase + i) * 256 + d];
            cv[i].x = v.x * wv.x; cv[i].y = v.y * wv.y;
            cv[i].z = v.z * wv.z; cv[i].w = v.w * wv.w;
        }
#pragma unroll
        for (int j = 0; j < 4; ++j)
            qv[j] = *(const float4*)&qo[((size_t)b * QL + qbase + j) * 256 + d];
#pragma unroll
        for (int i = 0; i < 4; ++i)
#pragma unroll
            for (int j = 0; j < 4; ++j)
                acc[i][j] += cv[i].x * qv[j].x + cv[i].y * qv[j].y +
                             cv[i].z * qv[j].z + cv[i].w * qv[j].w;
    }
    float ab = attb[0];
#pragma unroll
    for (int i = 0; i < 4; ++i) {
        float cwv = cw[b * CL + cbase + i];
#pragma unroll
        for (int j = 0; j < 4; ++j) {
            s[((size_t)b * CL + cbase + i) * QL + qbase + j] =
                acc[i][j] + cwv + qw[b * QL + qbase + j] + ab;
        }
    }
}

// ---------------------------------------------------------------------------
// softmax over q (64) per (b,c) row, in place; also writes row max (pre-softmax).
// one wave per row.
// ---------------------------------------------------------------------------
__global__ void softmax_q(float* __restrict__ s, float* __restrict__ smax)
{
    int gw   = (int)((blockIdx.x * blockDim.x + threadIdx.x) >> 6);
    int lane = threadIdx.x & 63;
    float v = s[(size_t)gw * QL + lane];
    float mx = v;
#pragma unroll
    for (int off = 32; off; off >>= 1) mx = fmaxf(mx, __shfl_xor(mx, off));
    float e = expf(v - mx);
    float sm = e;
#pragma unroll
    for (int off = 32; off; off >>= 1) sm += __shfl_xor(sm, off);
    s[(size_t)gw * QL + lane] = e / sm;
    if (lane == 0) smax[gw] = mx;
}

// ---------------------------------------------------------------------------
// bw[b,c] = softmax over c of smax[b,c]   (block per b, 512 threads)
// ---------------------------------------------------------------------------
__global__ __launch_bounds__(512)
void bw_k(const float* __restrict__ smax, float* __restrict__ bw)
{
    int b = blockIdx.x, c = threadIdx.x;
    int lane = c & 63, wid = c >> 6;
    __shared__ float red[8];
    float v = smax[b * CL + c];
    float mx = v;
#pragma unroll
    for (int off = 32; off; off >>= 1) mx = fmaxf(mx, __shfl_xor(mx, off));
    if (lane == 0) red[wid] = mx;
    __syncthreads();
    float bm = red[0];
#pragma unroll
    for (int w = 1; w < 8; ++w) bm = fmaxf(bm, red[w]);
    float e = expf(v - bm);
    float sm = e;
#pragma unroll
    for (int off = 32; off; off >>= 1) sm += __shfl_xor(sm, off);
    __syncthreads();
    if (lane == 0) red[wid] = sm;
    __syncthreads();
    float ts = 0.f;
#pragma unroll
    for (int w = 0; w < 8; ++w) ts += red[w];
    bw[b * CL + c] = e / ts;
}

// ---------------------------------------------------------------------------
// q2c[b,d] = sum_c bw[b,c] * co[b,c,d]   (block per b, 256 threads = d)
// ---------------------------------------------------------------------------
__global__ __launch_bounds__(256)
void q2c_k(const float* __restrict__ bw, const float* __restrict__ co,
           float* __restrict__ q2c)
{
    int b = blockIdx.x, d = threadIdx.x;
    float acc = 0.f;
    for (int c = 0; c < CL; ++c)
        acc += bw[b * CL + c] * co[((size_t)b * CL + c) * 256 + d];
    q2c[b * 256 + d] = acc;
}

// ---------------------------------------------------------------------------
// c2q + assemble g = [co, c2q, co*c2q, co*q2c]  (grid (B, CL/64), 256 thr)
// thread: one c row quarter-width: gq = tid&3 owns d-words {4gq+16jj}
// ---------------------------------------------------------------------------
__global__ __launch_bounds__(256)
void c2q_g(const float* __restrict__ a, const float* __restrict__ qo,
           const float* __restrict__ co, const float* __restrict__ q2c,
           float* __restrict__ g)
{
    int b  = blockIdx.x;
    int c  = blockIdx.y * 64 + (threadIdx.x >> 2);
    int gq = threadIdx.x & 3;

    float4 acc[16];
#pragma unroll
    for (int jj = 0; jj < 16; ++jj) acc[jj] = make_float4(0.f, 0.f, 0.f, 0.f);

    const float* ar = a + ((size_t)b * CL + c) * QL;
    for (int q = 0; q < QL; ++q) {
        float av = ar[q];
        const float* qr = qo + ((size_t)b * QL + q) * 256;
#pragma unroll
        for (int jj = 0; jj < 16; ++jj) {
            float4 qv = *(const float4*)&qr[4 * gq + 16 * jj];
            acc[jj].x += av * qv.x; acc[jj].y += av * qv.y;
            acc[jj].z += av * qv.z; acc[jj].w += av * qv.w;
        }
    }
    size_t gbase = ((size_t)b * CL + c) * 1024;
    const float* corow = co + ((size_t)b * CL + c) * 256;
    const float* q2cr  = q2c + b * 256;
#pragma unroll
    for (int jj = 0; jj < 16; ++jj) {
        int d = 4 * gq + 16 * jj;
        float4 cv = *(const float4*)&corow[d];
        float4 qc = *(const float4*)&q2cr[d];
        float4 cq = acc[jj];
        *(float4*)&g[gbase + d] = cv;
        *(float4*)&g[gbase + 256 + d] = cq;
        float4 t;
        t.x = cv.x * cq.x; t.y = cv.y * cq.y; t.z = cv.z * cq.z; t.w = cv.w * cq.w;
        *(float4*)&g[gbase + 512 + d] = t;
        t.x = cv.x * qc.x; t.y = cv.y * qc.y; t.z = cv.z * qc.z; t.w = cv.w * qc.w;
        *(float4*)&g[gbase + 768 + d] = t;
    }
}

// ---------------------------------------------------------------------------
// logits: lp1 = g.p1_wg + m.p1_wm + p1_b ; lp2 = g.p2_wg + m2o.p2_wm + p2_b
// one wave per row.
// ---------------------------------------------------------------------------
__global__ void logits_k(const float* __restrict__ g, const float* __restrict__ m,
                         const float* __restrict__ m2o,
                         const float* __restrict__ p1wg, const float* __restrict__ p1wm,
                         const float* __restrict__ p1b,
                         const float* __restrict__ p2wg, const float* __restrict__ p2wm,
                         const float* __restrict__ p2b,
                         float* __restrict__ lp1, float* __restrict__ lp2)
{
    int row  = (int)((blockIdx.x * blockDim.x + threadIdx.x) >> 6);
    int lane = threadIdx.x & 63;
    const float* gr = g + (size_t)row * 1024;
    float s1 = 0.f, s2 = 0.f;
    for (int d = lane; d < 1024; d += 64) {
        float gv = gr[d];
        s1 += gv * p1wg[d];
        s2 += gv * p2wg[d];
    }
    const float* mr  = m   + (size_t)row * 256;
    const float* m2r = m2o + (size_t)row * 256;
    for (int d = lane; d < 256; d += 64) {
        s1 += mr[d] * p1wm[d];
        s2 += m2r[d] * p2wm[d];
    }
#pragma unroll
    for (int off = 32; off; off >>= 1) {
        s1 += __shfl_down(s1, off);
        s2 += __shfl_down(s2, off);
    }
    if (lane == 0) {
        lp1[row] = s1 + p1b[0];
        lp2[row] = s2 + p2b[0];
    }
}

// ---------------------------------------------------------------------------
// masked softmax over C per batch. grid (B,2): y selects p1/p2.
// ---------------------------------------------------------------------------
__global__ __launch_bounds__(512)
void masked_softmax(const float* __restrict__ lp1, const float* __restrict__ lp2,
                    const int* __restrict__ p, float* __restrict__ out)
{
    int b = blockIdx.x, c = threadIdx.x;
    int lane = c & 63, wid = c >> 6;
    const float* lp = blockIdx.y ? lp2 : lp1;
    float* o = out + (size_t)blockIdx.y * BB * CL;

    __shared__ float red[8];
    float v = (p[b * CL + c] != 0) ? lp[b * CL + c] : -INFINITY;
    float mx = v;
#pragma unroll
    for (int off = 32; off; off >>= 1) mx = fmaxf(mx, __shfl_xor(mx, off));
    if (lane == 0) red[wid] = mx;
    __syncthreads();
    float bm = red[0];
#pragma unroll
    for (int w = 1; w < 8; ++w) bm = fmaxf(bm, red[w]);
    float e = expf(v - bm);
    float sm = e;
#pragma unroll
    for (int off = 32; off; off >>= 1) sm += __shfl_xor(sm, off);
    __syncthreads();
    if (lane == 0) red[wid] = sm;
    __syncthreads();
    float ts = 0.f;
#pragma unroll
    for (int w = 0; w < 8; ++w) ts += red[w];
    o[b * CL + c] = e / ts;
}

// ---------------------------------------------------------------------------
extern "C" void kernel_launch(void* const* d_in, const int* in_sizes, int n_in,
                              void* d_out, int out_size, void* d_ws, size_t ws_size,
                              hipStream_t stream)
{
    const int*   p        = (const int*)d_in[0];
    const int*   q        = (const int*)d_in[1];
    const float* emb      = (const float*)d_in[2];
    const float* qenc_Wih = (const float*)d_in[3];
    const float* qenc_Whh = (const float*)d_in[4];
    const float* qenc_b   = (const float*)d_in[5];
    const float* penc_Wih = (const float*)d_in[6];
    const float* penc_Whh = (const float*)d_in[7];
    const float* penc_b   = (const float*)d_in[8];
    const float* m1_Wih   = (const float*)d_in[9];
    const float* m1_Whh   = (const float*)d_in[10];
    const float* m1_b     = (const float*)d_in[11];
    const float* m2_Wih   = (const float*)d_in[12];
    const float* m2_Whh   = (const float*)d_in[13];
    const float* m2_b     = (const float*)d_in[14];
    const float* out_Wih  = (const float*)d_in[15];
    const float* out_Whh  = (const float*)d_in[16];
    const float* out_b    = (const float*)d_in[17];
    const float* att_wc   = (const float*)d_in[18];
    const float* att_wq   = (const float*)d_in[19];
    const float* att_wcq  = (const float*)d_in[20];
    const float* att_b    = (const float*)d_in[21];
    const float* p1_wg    = (const float*)d_in[22];
    const float* p1_wm    = (const float*)d_in[23];
    const float* p1_b     = (const float*)d_in[24];
    const float* p2_wg    = (const float*)d_in[25];
    const float* p2_wm    = (const float*)d_in[26];
    const float* p2_b     = (const float*)d_in[27];

    float* ws = (float*)d_ws;
    size_t off = 0;
    auto alloc = [&](size_t n) { float* r = ws + off; off += n; return r; };

    const size_t NC = (size_t)BB * CL;     // 32768
    const size_t NQ = (size_t)BB * QL;     // 4096

    float* xgA  = alloc(2 * NC * GATES);   // gate preacts, reused per layer
    float* gbuf = alloc(NC * 1024);        // g
    float* co   = alloc(NC * 256);
    float* qo   = alloc(NQ * 256);
    float* xgQ  = alloc(2 * NQ * GATES);
    float* sbuf = alloc(NC * QL);          // s, then a (in place)
    float* cw   = alloc(NC);
    float* qw   = alloc(NQ);
    float* smax = alloc(NC);
    float* bw   = alloc(NC);
    float* q2c  = alloc((size_t)BB * 256);
    float* mmid = alloc(NC * 256);
    float* mbuf = alloc(NC * 256);
    float* m2o  = alloc(NC * 256);
    float* lp1  = alloc(NC);
    float* lp2  = alloc(NC);
    (void)ws_size; (void)in_sizes; (void)n_in; (void)out_size;

    // ---- encoders ----
    gemm_xg<<<dim3((int)(NQ / 128), 4, 2), 256, 0, stream>>>(emb, q, qenc_Wih, qenc_b, xgQ, (int)NQ, 300);
    gemm_xg<<<dim3((int)(NC / 128), 4, 2), 256, 0, stream>>>(emb, p, penc_Wih, penc_b, xgA, (int)NC, 300);
    lstm_scan<<<dim3(BB, 2), 512, 0, stream>>>(xgQ, qenc_Whh, qo, QL);
    lstm_scan<<<dim3(BB, 2), 512, 0, stream>>>(xgA, penc_Whh, co, CL);

    // ---- attention ----
    rowdot<<<dim3((int)(NC * 64 / 256)), 256, 0, stream>>>(co, att_wc, cw, (int)NC, 256);
    rowdot<<<dim3((int)(NQ * 64 / 256)), 256, 0, stream>>>(qo, att_wq, qw, (int)NQ, 256);
    att_s<<<dim3(BB, CL / 64), 256, 0, stream>>>(co, qo, cw, qw, att_wcq, att_b, sbuf);
    softmax_q<<<dim3((int)(NC * 64 / 256)), 256, 0, stream>>>(sbuf, smax);
    bw_k<<<dim3(BB), 512, 0, stream>>>(smax, bw);
    q2c_k<<<dim3(BB), 256, 0, stream>>>(bw, co, q2c);
    c2q_g<<<dim3(BB, CL / 64), 256, 0, stream>>>(sbuf, qo, co, q2c, gbuf);

    // ---- modeling layers ----
    gemm_xg<<<dim3((int)(NC / 128), 4, 2), 256, 0, stream>>>(gbuf, nullptr, m1_Wih, m1_b, xgA, (int)NC, 1024);
    lstm_scan<<<dim3(BB, 2), 512, 0, stream>>>(xgA, m1_Whh, mmid, CL);
    gemm_xg<<<dim3((int)(NC / 128), 4, 2), 256, 0, stream>>>(mmid, nullptr, m2_Wih, m2_b, xgA, (int)NC, 256);
    lstm_scan<<<dim3(BB, 2), 512, 0, stream>>>(xgA, m2_Whh, mbuf, CL);
    gemm_xg<<<dim3((int)(NC / 128), 4, 2), 256, 0, stream>>>(mbuf, nullptr, out_Wih, out_b, xgA, (int)NC, 256);
    lstm_scan<<<dim3(BB, 2), 512, 0, stream>>>(xgA, out_Whh, m2o, CL);

    // ---- output ----
    logits_k<<<dim3((int)(NC * 64 / 256)), 256, 0, stream>>>(gbuf, mbuf, m2o,
        p1_wg, p1_wm, p1_b, p2_wg, p2_wm, p2_b, lp1, lp2);
    masked_softmax<<<dim3(BB, 2), 512, 0, stream>>>(lp1, lp2, p, (float*)d_out);
}

// Round 2
// 4241.949 us; speedup vs baseline: 1.1782x; 1.1782x over previous
//
#include <hip/hip_runtime.h>
#include <math.h>
#include <stdint.h>

#define HD    128      // hidden
#define GATES 512      // 4H
#define BB    64       // batch
#define CL    512      // context len
#define QL    64       // query len

#define TM 128
#define TN 128
#define TK 32

typedef __attribute__((ext_vector_type(8))) short short8_t;
typedef __attribute__((ext_vector_type(4))) short short4_t;
typedef __attribute__((ext_vector_type(4))) float f32x4;

__device__ __forceinline__ float sigmoidf_(float x) { return 1.f / (1.f + expf(-x)); }

// ---------------------------------------------------------------------------
// Split W (2*512, K) fp32 into 3 bf16 planes, each (2*512, Ksp), zero-padded.
// Truncation split: w = w1 + w2 + w3 + eps, |eps| <= 2^-24 |w|.
// Output layout: P[plane][row][k], plane stride 1024*Ksp.
// ---------------------------------------------------------------------------
__global__ __launch_bounds__(256)
void splitW_k(const float* __restrict__ W, ushort* __restrict__ P, int K, int Ksp)
{
    int idx = blockIdx.x * 256 + threadIdx.x;      // one per 4 outputs
    int per_row = Ksp >> 2;
    int total = 1024 * per_row;
    if (idx >= total) return;
    int row = idx / per_row;
    int c4  = (idx - row * per_row) * 4;

    short4_t o1, o2, o3;
#pragma unroll
    for (int e = 0; e < 4; ++e) {
        int k = c4 + e;
        float x = (k < K) ? W[(size_t)row * K + k] : 0.f;
        uint32_t u1 = __float_as_uint(x) & 0xffff0000u;
        float r1 = x - __uint_as_float(u1);
        uint32_t u2 = __float_as_uint(r1) & 0xffff0000u;
        float r2 = r1 - __uint_as_float(u2);
        uint32_t u3 = __float_as_uint(r2) & 0xffff0000u;
        o1[e] = (short)(u1 >> 16);
        o2[e] = (short)(u2 >> 16);
        o3[e] = (short)(u3 >> 16);
    }
    size_t base = (size_t)row * Ksp + c4;
    size_t ps = (size_t)1024 * Ksp;
    *reinterpret_cast<short4_t*>(&P[base]) = o1;
    *reinterpret_cast<short4_t*>(&P[ps + base]) = o2;
    *reinterpret_cast<short4_t*>(&P[2 * ps + base]) = o3;
}

// ---------------------------------------------------------------------------
// MFMA GEMM, bf16x3 split (6 cross-term MFMAs per k-tile):
//   C[m][n] = sum_k A[row(m)][k] * W[n][k] + bias[n]
// A fp32 row-major (lda=K), split on-the-fly during LDS staging.
// W pre-split planes (ushort), row stride Ksp, dir via blockIdx.z.
// Tiles 128x128x32, 4 waves (2x2), each wave 4x4 frags of 16x16x32.
// ---------------------------------------------------------------------------
__global__ __launch_bounds__(256)
void gemm_bf16x3(const float* __restrict__ A, const int* __restrict__ gidx,
                 const ushort* __restrict__ Wpl, const float* __restrict__ bias,
                 float* __restrict__ C, int M, int K, int Ksp)
{
    const int dir  = blockIdx.z;
    const int m0   = blockIdx.x * TM;
    const int n0   = blockIdx.y * TN;
    const int tid  = threadIdx.x;
    const int lane = tid & 63;
    const int wid  = tid >> 6;
    const int wm   = (wid >> 1) * 64;
    const int wn   = (wid & 1) * 64;

    __shared__ __align__(16) ushort As[3][TM * TK];
    __shared__ __align__(16) ushort Bs[3][TN * TK];

    const int ar = tid >> 3;          // 0..31 (4 rows per thread, +32 stride)
    const int ac = (tid & 7) * 4;     // k offset 0..28

    size_t arow[4];
#pragma unroll
    for (int r = 0; r < 4; ++r) {
        int m = m0 + ar + r * 32;
        arow[r] = gidx ? (size_t)gidx[m] : (size_t)m;
    }

    f32x4 acc[4][4];
#pragma unroll
    for (int i = 0; i < 4; ++i)
#pragma unroll
        for (int j = 0; j < 4; ++j) acc[i][j] = (f32x4)0.f;

    const size_t wps     = (size_t)1024 * Ksp;          // plane stride
    const size_t wdbase  = (size_t)dir * 512 * Ksp;     // dir offset within plane

    for (int k0 = 0; k0 < Ksp; k0 += TK) {
        // ---- stage A: load fp32, 3-way truncation split, ds_write ----
#pragma unroll
        for (int r = 0; r < 4; ++r) {
            float4 v = make_float4(0.f, 0.f, 0.f, 0.f);
            if (k0 + ac < K) v = *(const float4*)(A + arow[r] * K + k0 + ac);
            float xs[4] = {v.x, v.y, v.z, v.w};
            short4_t o1, o2, o3;
#pragma unroll
            for (int e = 0; e < 4; ++e) {
                uint32_t u1 = __float_as_uint(xs[e]) & 0xffff0000u;
                float r1 = xs[e] - __uint_as_float(u1);
                uint32_t u2 = __float_as_uint(r1) & 0xffff0000u;
                float r2 = r1 - __uint_as_float(u2);
                uint32_t u3 = __float_as_uint(r2) & 0xffff0000u;
                o1[e] = (short)(u1 >> 16);
                o2[e] = (short)(u2 >> 16);
                o3[e] = (short)(u3 >> 16);
            }
            int wb = (ar + r * 32) * TK + ac;
            *reinterpret_cast<short4_t*>(&As[0][wb]) = o1;
            *reinterpret_cast<short4_t*>(&As[1][wb]) = o2;
            *reinterpret_cast<short4_t*>(&As[2][wb]) = o3;
        }
        // ---- stage B: 24 chunks of 1KB via global_load_lds (6 per wave) ----
#pragma unroll
        for (int t = 0; t < 6; ++t) {
            int chunk = wid * 6 + t;      // 0..23
            int pl = chunk >> 3;          // plane 0..2
            int ch = chunk & 7;           // 8 chunks/plane: rows ch*16..+15
            int rrow = ch * 16 + (lane >> 2);
            const ushort* src = Wpl + (size_t)pl * wps + wdbase +
                                (size_t)(n0 + rrow) * Ksp + k0 + (lane & 3) * 8;
            ushort* dst = &Bs[pl][ch * 512];
            __builtin_amdgcn_global_load_lds(
                reinterpret_cast<const __attribute__((address_space(1))) void*>(
                    reinterpret_cast<uintptr_t>(src)),
                reinterpret_cast<__attribute__((address_space(3))) void*>(
                    reinterpret_cast<uintptr_t>(dst)),
                16, 0, 0);
        }
        __syncthreads();

        // ---- compute: 16 frag-pairs x 6 MFMAs ----
        const int koff = (lane >> 4) * 8;
        short8_t bf0[4], bf1[4], bf2[4];
#pragma unroll
        for (int j = 0; j < 4; ++j) {
            int nrow = wn + j * 16 + (lane & 15);
            bf0[j] = *reinterpret_cast<const short8_t*>(&Bs[0][nrow * TK + koff]);
            bf1[j] = *reinterpret_cast<const short8_t*>(&Bs[1][nrow * TK + koff]);
            bf2[j] = *reinterpret_cast<const short8_t*>(&Bs[2][nrow * TK + koff]);
        }
#pragma unroll
        for (int i = 0; i < 4; ++i) {
            int mrow = wm + i * 16 + (lane & 15);
            short8_t a1 = *reinterpret_cast<const short8_t*>(&As[0][mrow * TK + koff]);
            short8_t a2 = *reinterpret_cast<const short8_t*>(&As[1][mrow * TK + koff]);
            short8_t a3 = *reinterpret_cast<const short8_t*>(&As[2][mrow * TK + koff]);
#pragma unroll
            for (int j = 0; j < 4; ++j) {
                f32x4 c = acc[i][j];
                c = __builtin_amdgcn_mfma_f32_16x16x32_bf16(a1, bf0[j], c, 0, 0, 0);
                c = __builtin_amdgcn_mfma_f32_16x16x32_bf16(a1, bf1[j], c, 0, 0, 0);
                c = __builtin_amdgcn_mfma_f32_16x16x32_bf16(a2, bf0[j], c, 0, 0, 0);
                c = __builtin_amdgcn_mfma_f32_16x16x32_bf16(a2, bf1[j], c, 0, 0, 0);
                c = __builtin_amdgcn_mfma_f32_16x16x32_bf16(a1, bf2[j], c, 0, 0, 0);
                c = __builtin_amdgcn_mfma_f32_16x16x32_bf16(a3, bf0[j], c, 0, 0, 0);
                acc[i][j] = c;
            }
        }
        __syncthreads();
    }

    // ---- epilogue: bias + store (C/D map: col=lane&15, row=(lane>>4)*4+reg) ----
    float* Cd = C + (size_t)dir * M * 512;
#pragma unroll
    for (int j = 0; j < 4; ++j) {
        int col = n0 + wn + j * 16 + (lane & 15);
        float bv = bias[dir * 512 + col];
#pragma unroll
        for (int i = 0; i < 4; ++i) {
            int rbase = m0 + wm + i * 16 + ((lane >> 4) << 2);
#pragma unroll
            for (int r = 0; r < 4; ++r)
                Cd[(size_t)(rbase + r) * 512 + col] = acc[i][j][r] + bv;
        }
    }
}

// ---------------------------------------------------------------------------
// LSTM scan: one block per (batch, direction). 512 threads; thread j owns
// gate row j (Whh[j][0..127] in 128 VGPRs). h broadcast via LDS.
// xg layout (2,B,T,512); hout layout (B,T,256) with dir half offset.
// ---------------------------------------------------------------------------
__global__ __launch_bounds__(512)
void lstm_scan(const float* __restrict__ xg, const float* __restrict__ Whh,
               float* __restrict__ hout, int T)
{
    const int b   = blockIdx.x;
    const int dir = blockIdx.y;
    const int j   = threadIdx.x;

    const float* xgd = xg + (size_t)dir * BB * T * GATES;
    const float* wr  = Whh + ((size_t)dir * GATES + j) * HD;

    float4 w[32];
#pragma unroll
    for (int kk = 0; kk < 32; ++kk) w[kk] = *(const float4*)(wr + kk * 4);

    __shared__ __align__(16) float hs[HD];
    __shared__ float gs[GATES];

    if (j < HD) hs[j] = 0.f;
    float c = 0.f;
    __syncthreads();

    int t = dir ? (T - 1) : 0;
    const int dt = dir ? -1 : 1;

    float xcur = xgd[((size_t)b * T + t) * GATES + j];

    for (int step = 0; step < T; ++step) {
        int tn = t + dt;
        float xnext = (step + 1 < T) ? xgd[((size_t)b * T + tn) * GATES + j] : 0.f;

        float acc = xcur;
#pragma unroll
        for (int kk = 0; kk < 32; ++kk) {
            float4 h4 = *(const float4*)&hs[kk * 4];
            acc += w[kk].x * h4.x + w[kk].y * h4.y + w[kk].z * h4.z + w[kk].w * h4.w;
        }
        gs[j] = acc;
        __syncthreads();
        if (j < HD) {
            float ig = sigmoidf_(gs[j]);
            float fg = sigmoidf_(gs[HD + j]);
            float gg = tanhf(gs[2 * HD + j]);
            float og = sigmoidf_(gs[3 * HD + j]);
            c = fg * c + ig * gg;
            float h = og * tanhf(c);
            hs[j] = h;
            hout[((size_t)b * T + t) * 256 + dir * HD + j] = h;
        }
        __syncthreads();
        xcur = xnext;
        t = tn;
    }
}

// ---------------------------------------------------------------------------
__global__ void rowdot(const float* __restrict__ X, const float* __restrict__ w,
                       float* __restrict__ out, int N, int D)
{
    int gw   = (int)((blockIdx.x * blockDim.x + threadIdx.x) >> 6);
    int lane = threadIdx.x & 63;
    if (gw >= N) return;
    const float* xp = X + (size_t)gw * D;
    float s = 0.f;
    for (int d = lane; d < D; d += 64) s += xp[d] * w[d];
#pragma unroll
    for (int off = 32; off; off >>= 1) s += __shfl_down(s, off);
    if (lane == 0) out[gw] = s;
}

// ---------------------------------------------------------------------------
__global__ __launch_bounds__(256)
void att_s(const float* __restrict__ co, const float* __restrict__ qo,
           const float* __restrict__ cw, const float* __restrict__ qw,
           const float* __restrict__ wcq, const float* __restrict__ attb,
           float* __restrict__ s)
{
    int b  = blockIdx.x;
    int c0 = blockIdx.y * 64;
    int tid = threadIdx.x;
    int tq = tid & 15, trc = tid >> 4;
    int cbase = c0 + trc * 4, qbase = tq * 4;

    float acc[4][4];
#pragma unroll
    for (int i = 0; i < 4; ++i)
#pragma unroll
        for (int j = 0; j < 4; ++j) acc[i][j] = 0.f;

    for (int d = 0; d < 256; d += 4) {
        float4 wv = *(const float4*)&wcq[d];
        float4 cv[4], qv[4];
#pragma unroll
        for (int i = 0; i < 4; ++i) {
            float4 v = *(const float4*)&co[((size_t)b * CL + cbase + i) * 256 + d];
            cv[i].x = v.x * wv.x; cv[i].y = v.y * wv.y;
            cv[i].z = v.z * wv.z; cv[i].w = v.w * wv.w;
        }
#pragma unroll
        for (int j = 0; j < 4; ++j)
            qv[j] = *(const float4*)&qo[((size_t)b * QL + qbase + j) * 256 + d];
#pragma unroll
        for (int i = 0; i < 4; ++i)
#pragma unroll
            for (int j = 0; j < 4; ++j)
                acc[i][j] += cv[i].x * qv[j].x + cv[i].y * qv[j].y +
                             cv[i].z * qv[j].z + cv[i].w * qv[j].w;
    }
    float ab = attb[0];
#pragma unroll
    for (int i = 0; i < 4; ++i) {
        float cwv = cw[b * CL + cbase + i];
#pragma unroll
        for (int j = 0; j < 4; ++j) {
            s[((size_t)b * CL + cbase + i) * QL + qbase + j] =
                acc[i][j] + cwv + qw[b * QL + qbase + j] + ab;
        }
    }
}

// ---------------------------------------------------------------------------
__global__ void softmax_q(float* __restrict__ s, float* __restrict__ smax)
{
    int gw   = (int)((blockIdx.x * blockDim.x + threadIdx.x) >> 6);
    int lane = threadIdx.x & 63;
    float v = s[(size_t)gw * QL + lane];
    float mx = v;
#pragma unroll
    for (int off = 32; off; off >>= 1) mx = fmaxf(mx, __shfl_xor(mx, off));
    float e = expf(v - mx);
    float sm = e;
#pragma unroll
    for (int off = 32; off; off >>= 1) sm += __shfl_xor(sm, off);
    s[(size_t)gw * QL + lane] = e / sm;
    if (lane == 0) smax[gw] = mx;
}

// ---------------------------------------------------------------------------
__global__ __launch_bounds__(512)
void bw_k(const float* __restrict__ smax, float* __restrict__ bw)
{
    int b = blockIdx.x, c = threadIdx.x;
    int lane = c & 63, wid = c >> 6;
    __shared__ float red[8];
    float v = smax[b * CL + c];
    float mx = v;
#pragma unroll
    for (int off = 32; off; off >>= 1) mx = fmaxf(mx, __shfl_xor(mx, off));
    if (lane == 0) red[wid] = mx;
    __syncthreads();
    float bm = red[0];
#pragma unroll
    for (int w = 1; w < 8; ++w) bm = fmaxf(bm, red[w]);
    float e = expf(v - bm);
    float sm = e;
#pragma unroll
    for (int off = 32; off; off >>= 1) sm += __shfl_xor(sm, off);
    __syncthreads();
    if (lane == 0) red[wid] = sm;
    __syncthreads();
    float ts = 0.f;
#pragma unroll
    for (int w = 0; w < 8; ++w) ts += red[w];
    bw[b * CL + c] = e / ts;
}

// ---------------------------------------------------------------------------
__global__ __launch_bounds__(256)
void q2c_k(const float* __restrict__ bw, const float* __restrict__ co,
           float* __restrict__ q2c)
{
    int b = blockIdx.x, d = threadIdx.x;
    float acc = 0.f;
    for (int c = 0; c < CL; ++c)
        acc += bw[b * CL + c] * co[((size_t)b * CL + c) * 256 + d];
    q2c[b * 256 + d] = acc;
}

// ---------------------------------------------------------------------------
__global__ __launch_bounds__(256)
void c2q_g(const float* __restrict__ a, const float* __restrict__ qo,
           const float* __restrict__ co, const float* __restrict__ q2c,
           float* __restrict__ g)
{
    int b  = blockIdx.x;
    int c  = blockIdx.y * 64 + (threadIdx.x >> 2);
    int gq = threadIdx.x & 3;

    float4 acc[16];
#pragma unroll
    for (int jj = 0; jj < 16; ++jj) acc[jj] = make_float4(0.f, 0.f, 0.f, 0.f);

    const float* ar = a + ((size_t)b * CL + c) * QL;
    for (int q = 0; q < QL; ++q) {
        float av = ar[q];
        const float* qr = qo + ((size_t)b * QL + q) * 256;
#pragma unroll
        for (int jj = 0; jj < 16; ++jj) {
            float4 qv = *(const float4*)&qr[4 * gq + 16 * jj];
            acc[jj].x += av * qv.x; acc[jj].y += av * qv.y;
            acc[jj].z += av * qv.z; acc[jj].w += av * qv.w;
        }
    }
    size_t gbase = ((size_t)b * CL + c) * 1024;
    const float* corow = co + ((size_t)b * CL + c) * 256;
    const float* q2cr  = q2c + b * 256;
#pragma unroll
    for (int jj = 0; jj < 16; ++jj) {
        int d = 4 * gq + 16 * jj;
        float4 cv = *(const float4*)&corow[d];
        float4 qc = *(const float4*)&q2cr[d];
        float4 cq = acc[jj];
        *(float4*)&g[gbase + d] = cv;
        *(float4*)&g[gbase + 256 + d] = cq;
        float4 t;
        t.x = cv.x * cq.x; t.y = cv.y * cq.y; t.z = cv.z * cq.z; t.w = cv.w * cq.w;
        *(float4*)&g[gbase + 512 + d] = t;
        t.x = cv.x * qc.x; t.y = cv.y * qc.y; t.z = cv.z * qc.z; t.w = cv.w * qc.w;
        *(float4*)&g[gbase + 768 + d] = t;
    }
}

// ---------------------------------------------------------------------------
__global__ void logits_k(const float* __restrict__ g, const float* __restrict__ m,
                         const float* __restrict__ m2o,
                         const float* __restrict__ p1wg, const float* __restrict__ p1wm,
                         const float* __restrict__ p1b,
                         const float* __restrict__ p2wg, const float* __restrict__ p2wm,
                         const float* __restrict__ p2b,
                         float* __restrict__ lp1, float* __restrict__ lp2)
{
    int row  = (int)((blockIdx.x * blockDim.x + threadIdx.x) >> 6);
    int lane = threadIdx.x & 63;
    const float* gr = g + (size_t)row * 1024;
    float s1 = 0.f, s2 = 0.f;
    for (int d = lane; d < 1024; d += 64) {
        float gv = gr[d];
        s1 += gv * p1wg[d];
        s2 += gv * p2wg[d];
    }
    const float* mr  = m   + (size_t)row * 256;
    const float* m2r = m2o + (size_t)row * 256;
    for (int d = lane; d < 256; d += 64) {
        s1 += mr[d] * p1wm[d];
        s2 += m2r[d] * p2wm[d];
    }
#pragma unroll
    for (int off = 32; off; off >>= 1) {
        s1 += __shfl_down(s1, off);
        s2 += __shfl_down(s2, off);
    }
    if (lane == 0) {
        lp1[row] = s1 + p1b[0];
        lp2[row] = s2 + p2b[0];
    }
}

// ---------------------------------------------------------------------------
__global__ __launch_bounds__(512)
void masked_softmax(const float* __restrict__ lp1, const float* __restrict__ lp2,
                    const int* __restrict__ p, float* __restrict__ out)
{
    int b = blockIdx.x, c = threadIdx.x;
    int lane = c & 63, wid = c >> 6;
    const float* lp = blockIdx.y ? lp2 : lp1;
    float* o = out + (size_t)blockIdx.y * BB * CL;

    __shared__ float red[8];
    float v = (p[b * CL + c] != 0) ? lp[b * CL + c] : -INFINITY;
    float mx = v;
#pragma unroll
    for (int off = 32; off; off >>= 1) mx = fmaxf(mx, __shfl_xor(mx, off));
    if (lane == 0) red[wid] = mx;
    __syncthreads();
    float bm = red[0];
#pragma unroll
    for (int w = 1; w < 8; ++w) bm = fmaxf(bm, red[w]);
    float e = expf(v - bm);
    float sm = e;
#pragma unroll
    for (int off = 32; off; off >>= 1) sm += __shfl_xor(sm, off);
    __syncthreads();
    if (lane == 0) red[wid] = sm;
    __syncthreads();
    float ts = 0.f;
#pragma unroll
    for (int w = 0; w < 8; ++w) ts += red[w];
    o[b * CL + c] = e / ts;
}

// ---------------------------------------------------------------------------
extern "C" void kernel_launch(void* const* d_in, const int* in_sizes, int n_in,
                              void* d_out, int out_size, void* d_ws, size_t ws_size,
                              hipStream_t stream)
{
    const int*   p        = (const int*)d_in[0];
    const int*   q        = (const int*)d_in[1];
    const float* emb      = (const float*)d_in[2];
    const float* qenc_Wih = (const float*)d_in[3];
    const float* qenc_Whh = (const float*)d_in[4];
    const float* qenc_b   = (const float*)d_in[5];
    const float* penc_Wih = (const float*)d_in[6];
    const float* penc_Whh = (const float*)d_in[7];
    const float* penc_b   = (const float*)d_in[8];
    const float* m1_Wih   = (const float*)d_in[9];
    const float* m1_Whh   = (const float*)d_in[10];
    const float* m1_b     = (const float*)d_in[11];
    const float* m2_Wih   = (const float*)d_in[12];
    const float* m2_Whh   = (const float*)d_in[13];
    const float* m2_b     = (const float*)d_in[14];
    const float* out_Wih  = (const float*)d_in[15];
    const float* out_Whh  = (const float*)d_in[16];
    const float* out_b    = (const float*)d_in[17];
    const float* att_wc   = (const float*)d_in[18];
    const float* att_wq   = (const float*)d_in[19];
    const float* att_wcq  = (const float*)d_in[20];
    const float* att_b    = (const float*)d_in[21];
    const float* p1_wg    = (const float*)d_in[22];
    const float* p1_wm    = (const float*)d_in[23];
    const float* p1_b     = (const float*)d_in[24];
    const float* p2_wg    = (const float*)d_in[25];
    const float* p2_wm    = (const float*)d_in[26];
    const float* p2_b     = (const float*)d_in[27];

    float* ws = (float*)d_ws;
    size_t off = 0;
    auto alloc = [&](size_t n) { float* r = ws + off; off += n; return r; };
    auto allocU = [&](size_t nsh) { ushort* r = (ushort*)(ws + off); off += (nsh + 1) / 2; return r; };

    const size_t NC = (size_t)BB * CL;     // 32768
    const size_t NQ = (size_t)BB * QL;     // 4096

    float* xgA  = alloc(2 * NC * GATES);   // gate preacts, reused per layer
    float* gbuf = alloc(NC * 1024);        // g  (xgQ aliases its head: dead before g written)
    float* xgQ  = gbuf;
    float* co   = alloc(NC * 256);
    float* qo   = alloc(NQ * 256);
    float* sbuf = alloc(NC * QL);          // s, then a (in place)
    float* cw   = alloc(NC);
    float* qw   = alloc(NQ);
    float* smax = alloc(NC);
    float* bw   = alloc(NC);
    float* q2c  = alloc((size_t)BB * 256);
    float* mmid = alloc(NC * 256);
    float* mbuf = alloc(NC * 256);
    float* m2o  = alloc(NC * 256);
    float* lp1  = alloc(NC);
    float* lp2  = alloc(NC);
    // bf16 weight planes: [3][1024][Ksp]
    ushort* WqP  = allocU((size_t)3 * 1024 * 320);
    ushort* WpP  = allocU((size_t)3 * 1024 * 320);
    ushort* Wm1P = allocU((size_t)3 * 1024 * 1024);
    ushort* Wm2P = allocU((size_t)3 * 1024 * 256);
    ushort* WoP  = allocU((size_t)3 * 1024 * 256);
    (void)ws_size; (void)in_sizes; (void)n_in; (void)out_size;

    // ---- weight splits (independent; run upfront) ----
    splitW_k<<<dim3(1024 * 80 / 256), 256, 0, stream>>>(qenc_Wih, WqP, 300, 320);
    splitW_k<<<dim3(1024 * 80 / 256), 256, 0, stream>>>(penc_Wih, WpP, 300, 320);
    splitW_k<<<dim3(1024 * 256 / 256), 256, 0, stream>>>(m1_Wih, Wm1P, 1024, 1024);
    splitW_k<<<dim3(1024 * 64 / 256), 256, 0, stream>>>(m2_Wih, Wm2P, 256, 256);
    splitW_k<<<dim3(1024 * 64 / 256), 256, 0, stream>>>(out_Wih, WoP, 256, 256);

    // ---- encoders ----
    gemm_bf16x3<<<dim3((int)(NQ / TM), 4, 2), 256, 0, stream>>>(emb, q, WqP, qenc_b, xgQ, (int)NQ, 300, 320);
    gemm_bf16x3<<<dim3((int)(NC / TM), 4, 2), 256, 0, stream>>>(emb, p, WpP, penc_b, xgA, (int)NC, 300, 320);
    lstm_scan<<<dim3(BB, 2), 512, 0, stream>>>(xgQ, qenc_Whh, qo, QL);
    lstm_scan<<<dim3(BB, 2), 512, 0, stream>>>(xgA, penc_Whh, co, CL);

    // ---- attention ----
    rowdot<<<dim3((int)(NC * 64 / 256)), 256, 0, stream>>>(co, att_wc, cw, (int)NC, 256);
    rowdot<<<dim3((int)(NQ * 64 / 256)), 256, 0, stream>>>(qo, att_wq, qw, (int)NQ, 256);
    att_s<<<dim3(BB, CL / 64), 256, 0, stream>>>(co, qo, cw, qw, att_wcq, att_b, sbuf);
    softmax_q<<<dim3((int)(NC * 64 / 256)), 256, 0, stream>>>(sbuf, smax);
    bw_k<<<dim3(BB), 512, 0, stream>>>(smax, bw);
    q2c_k<<<dim3(BB), 256, 0, stream>>>(bw, co, q2c);
    c2q_g<<<dim3(BB, CL / 64), 256, 0, stream>>>(sbuf, qo, co, q2c, gbuf);

    // ---- modeling layers ----
    gemm_bf16x3<<<dim3((int)(NC / TM), 4, 2), 256, 0, stream>>>(gbuf, nullptr, Wm1P, m1_b, xgA, (int)NC, 1024, 1024);
    lstm_scan<<<dim3(BB, 2), 512, 0, stream>>>(xgA, m1_Whh, mmid, CL);
    gemm_bf16x3<<<dim3((int)(NC / TM), 4, 2), 256, 0, stream>>>(mmid, nullptr, Wm2P, m2_b, xgA, (int)NC, 256, 256);
    lstm_scan<<<dim3(BB, 2), 512, 0, stream>>>(xgA, m2_Whh, mbuf, CL);
    gemm_bf16x3<<<dim3((int)(NC / TM), 4, 2), 256, 0, stream>>>(mbuf, nullptr, WoP, out_b, xgA, (int)NC, 256, 256);
    lstm_scan<<<dim3(BB, 2), 512, 0, stream>>>(xgA, out_Whh, m2o, CL);

    // ---- output ----
    logits_k<<<dim3((int)(NC * 64 / 256)), 256, 0, stream>>>(gbuf, mbuf, m2o,
        p1_wg, p1_wm, p1_b, p2_wg, p2_wm, p2_b, lp1, lp2);
    masked_softmax<<<dim3(BB, 2), 512, 0, stream>>>(lp1, lp2, p, (float*)d_out);
}

// Round 3
// 3586.409 us; speedup vs baseline: 1.3936x; 1.1828x over previous
//
#include <hip/hip_runtime.h>
#include <math.h>
#include <stdint.h>

#define HD    128      // hidden
#define GATES 512      // 4H
#define BB    64       // batch
#define CL    512      // context len
#define QL    64       // query len

#define TM 128
#define TN 128
#define TK 32

typedef __attribute__((ext_vector_type(8))) short short8_t;
typedef __attribute__((ext_vector_type(4))) short short4_t;
typedef __attribute__((ext_vector_type(4))) float f32x4;

__device__ __forceinline__ float fast_sigmoid(float x) {
    float e = __builtin_amdgcn_exp2f(-1.44269504f * x);
    return __builtin_amdgcn_rcpf(1.f + e);
}
__device__ __forceinline__ float fast_tanh(float x) {
    // tanh(x) = 1 - 2/(exp2(2x*log2e)+1); saturates correctly at +-inf
    float e = __builtin_amdgcn_exp2f(2.88539008f * x);
    float r = __builtin_amdgcn_rcpf(e + 1.f);
    return 1.f - 2.f * r;
}

// ---------------------------------------------------------------------------
// Split W (2*512, K) fp32 into 3 bf16 planes, each (2*512, Ksp), zero-padded.
// ---------------------------------------------------------------------------
__global__ __launch_bounds__(256)
void splitW_k(const float* __restrict__ W, ushort* __restrict__ P, int K, int Ksp)
{
    int idx = blockIdx.x * 256 + threadIdx.x;
    int per_row = Ksp >> 2;
    int total = 1024 * per_row;
    if (idx >= total) return;
    int row = idx / per_row;
    int c4  = (idx - row * per_row) * 4;

    short4_t o1, o2, o3;
#pragma unroll
    for (int e = 0; e < 4; ++e) {
        int k = c4 + e;
        float x = (k < K) ? W[(size_t)row * K + k] : 0.f;
        uint32_t u1 = __float_as_uint(x) & 0xffff0000u;
        float r1 = x - __uint_as_float(u1);
        uint32_t u2 = __float_as_uint(r1) & 0xffff0000u;
        float r2 = r1 - __uint_as_float(u2);
        uint32_t u3 = __float_as_uint(r2) & 0xffff0000u;
        o1[e] = (short)(u1 >> 16);
        o2[e] = (short)(u2 >> 16);
        o3[e] = (short)(u3 >> 16);
    }
    size_t base = (size_t)row * Ksp + c4;
    size_t ps = (size_t)1024 * Ksp;
    *reinterpret_cast<short4_t*>(&P[base]) = o1;
    *reinterpret_cast<short4_t*>(&P[ps + base]) = o2;
    *reinterpret_cast<short4_t*>(&P[2 * ps + base]) = o3;
}

// ---------------------------------------------------------------------------
// MFMA GEMM, bf16x3 split (6 cross-term MFMAs per k-tile).
// ---------------------------------------------------------------------------
__global__ __launch_bounds__(256)
void gemm_bf16x3(const float* __restrict__ A, const int* __restrict__ gidx,
                 const ushort* __restrict__ Wpl, const float* __restrict__ bias,
                 float* __restrict__ C, int M, int K, int Ksp)
{
    const int dir  = blockIdx.z;
    const int m0   = blockIdx.x * TM;
    const int n0   = blockIdx.y * TN;
    const int tid  = threadIdx.x;
    const int lane = tid & 63;
    const int wid  = tid >> 6;
    const int wm   = (wid >> 1) * 64;
    const int wn   = (wid & 1) * 64;

    __shared__ __align__(16) ushort As[3][TM * TK];
    __shared__ __align__(16) ushort Bs[3][TN * TK];

    const int ar = tid >> 3;
    const int ac = (tid & 7) * 4;

    size_t arow[4];
#pragma unroll
    for (int r = 0; r < 4; ++r) {
        int m = m0 + ar + r * 32;
        arow[r] = gidx ? (size_t)gidx[m] : (size_t)m;
    }

    f32x4 acc[4][4];
#pragma unroll
    for (int i = 0; i < 4; ++i)
#pragma unroll
        for (int j = 0; j < 4; ++j) acc[i][j] = (f32x4)0.f;

    const size_t wps    = (size_t)1024 * Ksp;
    const size_t wdbase = (size_t)dir * 512 * Ksp;

    for (int k0 = 0; k0 < Ksp; k0 += TK) {
#pragma unroll
        for (int r = 0; r < 4; ++r) {
            float4 v = make_float4(0.f, 0.f, 0.f, 0.f);
            if (k0 + ac < K) v = *(const float4*)(A + arow[r] * K + k0 + ac);
            float xs[4] = {v.x, v.y, v.z, v.w};
            short4_t o1, o2, o3;
#pragma unroll
            for (int e = 0; e < 4; ++e) {
                uint32_t u1 = __float_as_uint(xs[e]) & 0xffff0000u;
                float r1 = xs[e] - __uint_as_float(u1);
                uint32_t u2 = __float_as_uint(r1) & 0xffff0000u;
                float r2 = r1 - __uint_as_float(u2);
                uint32_t u3 = __float_as_uint(r2) & 0xffff0000u;
                o1[e] = (short)(u1 >> 16);
                o2[e] = (short)(u2 >> 16);
                o3[e] = (short)(u3 >> 16);
            }
            int wb = (ar + r * 32) * TK + ac;
            *reinterpret_cast<short4_t*>(&As[0][wb]) = o1;
            *reinterpret_cast<short4_t*>(&As[1][wb]) = o2;
            *reinterpret_cast<short4_t*>(&As[2][wb]) = o3;
        }
#pragma unroll
        for (int t = 0; t < 6; ++t) {
            int chunk = wid * 6 + t;
            int pl = chunk >> 3;
            int ch = chunk & 7;
            int rrow = ch * 16 + (lane >> 2);
            const ushort* src = Wpl + (size_t)pl * wps + wdbase +
                                (size_t)(n0 + rrow) * Ksp + k0 + (lane & 3) * 8;
            ushort* dst = &Bs[pl][ch * 512];
            __builtin_amdgcn_global_load_lds(
                reinterpret_cast<const __attribute__((address_space(1))) void*>(
                    reinterpret_cast<uintptr_t>(src)),
                reinterpret_cast<__attribute__((address_space(3))) void*>(
                    reinterpret_cast<uintptr_t>(dst)),
                16, 0, 0);
        }
        __syncthreads();

        const int koff = (lane >> 4) * 8;
        short8_t bf0[4], bf1[4], bf2[4];
#pragma unroll
        for (int j = 0; j < 4; ++j) {
            int nrow = wn + j * 16 + (lane & 15);
            bf0[j] = *reinterpret_cast<const short8_t*>(&Bs[0][nrow * TK + koff]);
            bf1[j] = *reinterpret_cast<const short8_t*>(&Bs[1][nrow * TK + koff]);
            bf2[j] = *reinterpret_cast<const short8_t*>(&Bs[2][nrow * TK + koff]);
        }
#pragma unroll
        for (int i = 0; i < 4; ++i) {
            int mrow = wm + i * 16 + (lane & 15);
            short8_t a1 = *reinterpret_cast<const short8_t*>(&As[0][mrow * TK + koff]);
            short8_t a2 = *reinterpret_cast<const short8_t*>(&As[1][mrow * TK + koff]);
            short8_t a3 = *reinterpret_cast<const short8_t*>(&As[2][mrow * TK + koff]);
#pragma unroll
            for (int j = 0; j < 4; ++j) {
                f32x4 c = acc[i][j];
                c = __builtin_amdgcn_mfma_f32_16x16x32_bf16(a1, bf0[j], c, 0, 0, 0);
                c = __builtin_amdgcn_mfma_f32_16x16x32_bf16(a1, bf1[j], c, 0, 0, 0);
                c = __builtin_amdgcn_mfma_f32_16x16x32_bf16(a2, bf0[j], c, 0, 0, 0);
                c = __builtin_amdgcn_mfma_f32_16x16x32_bf16(a2, bf1[j], c, 0, 0, 0);
                c = __builtin_amdgcn_mfma_f32_16x16x32_bf16(a1, bf2[j], c, 0, 0, 0);
                c = __builtin_amdgcn_mfma_f32_16x16x32_bf16(a3, bf0[j], c, 0, 0, 0);
                acc[i][j] = c;
            }
        }
        __syncthreads();
    }

    float* Cd = C + (size_t)dir * M * 512;
#pragma unroll
    for (int j = 0; j < 4; ++j) {
        int col = n0 + wn + j * 16 + (lane & 15);
        float bv = bias[dir * 512 + col];
#pragma unroll
        for (int i = 0; i < 4; ++i) {
            int rbase = m0 + wm + i * 16 + ((lane >> 4) << 2);
#pragma unroll
            for (int r = 0; r < 4; ++r)
                Cd[(size_t)(rbase + r) * 512 + col] = acc[i][j][r] + bv;
        }
    }
}

// ---------------------------------------------------------------------------
// LSTM scan v2: block per (batch, dir[, layer via z]); 512 threads; thread j
// owns gate row j. 8-accumulator dot (short dep chains), all-thread fast
// activations, h broadcast via LDS. z=0: P-layer params, z=1: Q-layer params.
// ---------------------------------------------------------------------------
__global__ __launch_bounds__(512)
void lstm_scan2(const float* __restrict__ xgP, const float* __restrict__ WhhP,
                float* __restrict__ hoP, int TP,
                const float* __restrict__ xgQ, const float* __restrict__ WhhQ,
                float* __restrict__ hoQ, int TQ)
{
    const int b   = blockIdx.x;
    const int dir = blockIdx.y;
    const int j   = threadIdx.x;

    const float* xg; const float* Whh; float* ho; int T;
    if (blockIdx.z == 0) { xg = xgP; Whh = WhhP; ho = hoP; T = TP; }
    else                 { xg = xgQ; Whh = WhhQ; ho = hoQ; T = TQ; }

    const float* xgd = xg + (size_t)dir * BB * T * GATES;
    const float* wr  = Whh + ((size_t)dir * GATES + j) * HD;

    float4 w[32];
#pragma unroll
    for (int kk = 0; kk < 32; ++kk) w[kk] = *(const float4*)(wr + kk * 4);

    __shared__ __align__(16) float hs[HD];
    __shared__ float gs[GATES];

    if (j < HD) hs[j] = 0.f;
    float c = 0.f;
    __syncthreads();

    int t = dir ? (T - 1) : 0;
    const int dt = dir ? -1 : 1;
    const int gtype = j >> 7;            // 0:i 1:f 2:g 3:o (wave-uniform)

    float xcur = xgd[((size_t)b * T + t) * GATES + j];

    for (int step = 0; step < T; ++step) {
        int tn = t + dt;
        float xnext = (step + 1 < T) ? xgd[((size_t)b * T + tn) * GATES + j] : 0.f;

        float av[8];
        av[0] = xcur;
#pragma unroll
        for (int u = 1; u < 8; ++u) av[u] = 0.f;
#pragma unroll
        for (int kk = 0; kk < 32; ++kk) {
            float4 h4 = *(const float4*)&hs[kk * 4];
            float a = av[kk & 7];
            a += w[kk].x * h4.x;
            a += w[kk].y * h4.y;
            a += w[kk].z * h4.z;
            a += w[kk].w * h4.w;
            av[kk & 7] = a;
        }
        float pre = ((av[0] + av[4]) + (av[1] + av[5])) +
                    ((av[2] + av[6]) + (av[3] + av[7]));
        float act = (gtype == 2) ? fast_tanh(pre) : fast_sigmoid(pre);
        gs[j] = act;
        __syncthreads();
        if (j < HD) {
            float ig = gs[j], fg = gs[HD + j], gg = gs[2 * HD + j], og = gs[3 * HD + j];
            c = fg * c + ig * gg;
            float h = og * fast_tanh(c);
            hs[j] = h;
            ho[((size_t)b * T + t) * 256 + dir * HD + j] = h;
        }
        __syncthreads();
        xcur = xnext;
        t = tn;
    }
}

// ---------------------------------------------------------------------------
__global__ void rowdot(const float* __restrict__ X, const float* __restrict__ w,
                       float* __restrict__ out, int N, int D)
{
    int gw   = (int)((blockIdx.x * blockDim.x + threadIdx.x) >> 6);
    int lane = threadIdx.x & 63;
    if (gw >= N) return;
    const float* xp = X + (size_t)gw * D;
    float s = 0.f;
    for (int d = lane; d < D; d += 64) s += xp[d] * w[d];
#pragma unroll
    for (int off = 32; off; off >>= 1) s += __shfl_down(s, off);
    if (lane == 0) out[gw] = s;
}

// ---------------------------------------------------------------------------
__global__ __launch_bounds__(256)
void att_s(const float* __restrict__ co, const float* __restrict__ qo,
           const float* __restrict__ cw, const float* __restrict__ qw,
           const float* __restrict__ wcq, const float* __restrict__ attb,
           float* __restrict__ s)
{
    int b  = blockIdx.x;
    int c0 = blockIdx.y * 64;
    int tid = threadIdx.x;
    int tq = tid & 15, trc = tid >> 4;
    int cbase = c0 + trc * 4, qbase = tq * 4;

    float acc[4][4];
#pragma unroll
    for (int i = 0; i < 4; ++i)
#pragma unroll
        for (int j = 0; j < 4; ++j) acc[i][j] = 0.f;

    for (int d = 0; d < 256; d += 4) {
        float4 wv = *(const float4*)&wcq[d];
        float4 cv[4], qv[4];
#pragma unroll
        for (int i = 0; i < 4; ++i) {
            float4 v = *(const float4*)&co[((size_t)b * CL + cbase + i) * 256 + d];
            cv[i].x = v.x * wv.x; cv[i].y = v.y * wv.y;
            cv[i].z = v.z * wv.z; cv[i].w = v.w * wv.w;
        }
#pragma unroll
        for (int j = 0; j < 4; ++j)
            qv[j] = *(const float4*)&qo[((size_t)b * QL + qbase + j) * 256 + d];
#pragma unroll
        for (int i = 0; i < 4; ++i)
#pragma unroll
            for (int j = 0; j < 4; ++j)
                acc[i][j] += cv[i].x * qv[j].x + cv[i].y * qv[j].y +
                             cv[i].z * qv[j].z + cv[i].w * qv[j].w;
    }
    float ab = attb[0];
#pragma unroll
    for (int i = 0; i < 4; ++i) {
        float cwv = cw[b * CL + cbase + i];
#pragma unroll
        for (int j = 0; j < 4; ++j) {
            s[((size_t)b * CL + cbase + i) * QL + qbase + j] =
                acc[i][j] + cwv + qw[b * QL + qbase + j] + ab;
        }
    }
}

// ---------------------------------------------------------------------------
__global__ void softmax_q(float* __restrict__ s, float* __restrict__ smax)
{
    int gw   = (int)((blockIdx.x * blockDim.x + threadIdx.x) >> 6);
    int lane = threadIdx.x & 63;
    float v = s[(size_t)gw * QL + lane];
    float mx = v;
#pragma unroll
    for (int off = 32; off; off >>= 1) mx = fmaxf(mx, __shfl_xor(mx, off));
    float e = expf(v - mx);
    float sm = e;
#pragma unroll
    for (int off = 32; off; off >>= 1) sm += __shfl_xor(sm, off);
    s[(size_t)gw * QL + lane] = e / sm;
    if (lane == 0) smax[gw] = mx;
}

// ---------------------------------------------------------------------------
__global__ __launch_bounds__(512)
void bw_k(const float* __restrict__ smax, float* __restrict__ bw)
{
    int b = blockIdx.x, c = threadIdx.x;
    int lane = c & 63, wid = c >> 6;
    __shared__ float red[8];
    float v = smax[b * CL + c];
    float mx = v;
#pragma unroll
    for (int off = 32; off; off >>= 1) mx = fmaxf(mx, __shfl_xor(mx, off));
    if (lane == 0) red[wid] = mx;
    __syncthreads();
    float bm = red[0];
#pragma unroll
    for (int w = 1; w < 8; ++w) bm = fmaxf(bm, red[w]);
    float e = expf(v - bm);
    float sm = e;
#pragma unroll
    for (int off = 32; off; off >>= 1) sm += __shfl_xor(sm, off);
    __syncthreads();
    if (lane == 0) red[wid] = sm;
    __syncthreads();
    float ts = 0.f;
#pragma unroll
    for (int w = 0; w < 8; ++w) ts += red[w];
    bw[b * CL + c] = e / ts;
}

// ---------------------------------------------------------------------------
__global__ __launch_bounds__(256)
void q2c_k(const float* __restrict__ bw, const float* __restrict__ co,
           float* __restrict__ q2c)
{
    int b = blockIdx.x, d = threadIdx.x;
    float acc = 0.f;
    for (int c = 0; c < CL; ++c)
        acc += bw[b * CL + c] * co[((size_t)b * CL + c) * 256 + d];
    q2c[b * 256 + d] = acc;
}

// ---------------------------------------------------------------------------
__global__ __launch_bounds__(256)
void c2q_g(const float* __restrict__ a, const float* __restrict__ qo,
           const float* __restrict__ co, const float* __restrict__ q2c,
           float* __restrict__ g)
{
    int b  = blockIdx.x;
    int c  = blockIdx.y * 64 + (threadIdx.x >> 2);
    int gq = threadIdx.x & 3;

    float4 acc[16];
#pragma unroll
    for (int jj = 0; jj < 16; ++jj) acc[jj] = make_float4(0.f, 0.f, 0.f, 0.f);

    const float* ar = a + ((size_t)b * CL + c) * QL;
    for (int q = 0; q < QL; ++q) {
        float av = ar[q];
        const float* qr = qo + ((size_t)b * QL + q) * 256;
#pragma unroll
        for (int jj = 0; jj < 16; ++jj) {
            float4 qv = *(const float4*)&qr[4 * gq + 16 * jj];
            acc[jj].x += av * qv.x; acc[jj].y += av * qv.y;
            acc[jj].z += av * qv.z; acc[jj].w += av * qv.w;
        }
    }
    size_t gbase = ((size_t)b * CL + c) * 1024;
    const float* corow = co + ((size_t)b * CL + c) * 256;
    const float* q2cr  = q2c + b * 256;
#pragma unroll
    for (int jj = 0; jj < 16; ++jj) {
        int d = 4 * gq + 16 * jj;
        float4 cv = *(const float4*)&corow[d];
        float4 qc = *(const float4*)&q2cr[d];
        float4 cq = acc[jj];
        *(float4*)&g[gbase + d] = cv;
        *(float4*)&g[gbase + 256 + d] = cq;
        float4 t;
        t.x = cv.x * cq.x; t.y = cv.y * cq.y; t.z = cv.z * cq.z; t.w = cv.w * cq.w;
        *(float4*)&g[gbase + 512 + d] = t;
        t.x = cv.x * qc.x; t.y = cv.y * qc.y; t.z = cv.z * qc.z; t.w = cv.w * qc.w;
        *(float4*)&g[gbase + 768 + d] = t;
    }
}

// ---------------------------------------------------------------------------
__global__ void logits_k(const float* __restrict__ g, const float* __restrict__ m,
                         const float* __restrict__ m2o,
                         const float* __restrict__ p1wg, const float* __restrict__ p1wm,
                         const float* __restrict__ p1b,
                         const float* __restrict__ p2wg, const float* __restrict__ p2wm,
                         const float* __restrict__ p2b,
                         float* __restrict__ lp1, float* __restrict__ lp2)
{
    int row  = (int)((blockIdx.x * blockDim.x + threadIdx.x) >> 6);
    int lane = threadIdx.x & 63;
    const float* gr = g + (size_t)row * 1024;
    float s1 = 0.f, s2 = 0.f;
    for (int d = lane; d < 1024; d += 64) {
        float gv = gr[d];
        s1 += gv * p1wg[d];
        s2 += gv * p2wg[d];
    }
    const float* mr  = m   + (size_t)row * 256;
    const float* m2r = m2o + (size_t)row * 256;
    for (int d = lane; d < 256; d += 64) {
        s1 += mr[d] * p1wm[d];
        s2 += m2r[d] * p2wm[d];
    }
#pragma unroll
    for (int off = 32; off; off >>= 1) {
        s1 += __shfl_down(s1, off);
        s2 += __shfl_down(s2, off);
    }
    if (lane == 0) {
        lp1[row] = s1 + p1b[0];
        lp2[row] = s2 + p2b[0];
    }
}

// ---------------------------------------------------------------------------
__global__ __launch_bounds__(512)
void masked_softmax(const float* __restrict__ lp1, const float* __restrict__ lp2,
                    const int* __restrict__ p, float* __restrict__ out)
{
    int b = blockIdx.x, c = threadIdx.x;
    int lane = c & 63, wid = c >> 6;
    const float* lp = blockIdx.y ? lp2 : lp1;
    float* o = out + (size_t)blockIdx.y * BB * CL;

    __shared__ float red[8];
    float v = (p[b * CL + c] != 0) ? lp[b * CL + c] : -INFINITY;
    float mx = v;
#pragma unroll
    for (int off = 32; off; off >>= 1) mx = fmaxf(mx, __shfl_xor(mx, off));
    if (lane == 0) red[wid] = mx;
    __syncthreads();
    float bm = red[0];
#pragma unroll
    for (int w = 1; w < 8; ++w) bm = fmaxf(bm, red[w]);
    float e = expf(v - bm);
    float sm = e;
#pragma unroll
    for (int off = 32; off; off >>= 1) sm += __shfl_xor(sm, off);
    __syncthreads();
    if (lane == 0) red[wid] = sm;
    __syncthreads();
    float ts = 0.f;
#pragma unroll
    for (int w = 0; w < 8; ++w) ts += red[w];
    o[b * CL + c] = e / ts;
}

// ---------------------------------------------------------------------------
extern "C" void kernel_launch(void* const* d_in, const int* in_sizes, int n_in,
                              void* d_out, int out_size, void* d_ws, size_t ws_size,
                              hipStream_t stream)
{
    const int*   p        = (const int*)d_in[0];
    const int*   q        = (const int*)d_in[1];
    const float* emb      = (const float*)d_in[2];
    const float* qenc_Wih = (const float*)d_in[3];
    const float* qenc_Whh = (const float*)d_in[4];
    const float* qenc_b   = (const float*)d_in[5];
    const float* penc_Wih = (const float*)d_in[6];
    const float* penc_Whh = (const float*)d_in[7];
    const float* penc_b   = (const float*)d_in[8];
    const float* m1_Wih   = (const float*)d_in[9];
    const float* m1_Whh   = (const float*)d_in[10];
    const float* m1_b     = (const float*)d_in[11];
    const float* m2_Wih   = (const float*)d_in[12];
    const float* m2_Whh   = (const float*)d_in[13];
    const float* m2_b     = (const float*)d_in[14];
    const float* out_Wih  = (const float*)d_in[15];
    const float* out_Whh  = (const float*)d_in[16];
    const float* out_b    = (const float*)d_in[17];
    const float* att_wc   = (const float*)d_in[18];
    const float* att_wq   = (const float*)d_in[19];
    const float* att_wcq  = (const float*)d_in[20];
    const float* att_b    = (const float*)d_in[21];
    const float* p1_wg    = (const float*)d_in[22];
    const float* p1_wm    = (const float*)d_in[23];
    const float* p1_b     = (const float*)d_in[24];
    const float* p2_wg    = (const float*)d_in[25];
    const float* p2_wm    = (const float*)d_in[26];
    const float* p2_b     = (const float*)d_in[27];

    float* ws = (float*)d_ws;
    size_t off = 0;
    auto alloc = [&](size_t n) { float* r = ws + off; off += n; return r; };
    auto allocU = [&](size_t nsh) { ushort* r = (ushort*)(ws + off); off += (nsh + 1) / 2; return r; };

    const size_t NC = (size_t)BB * CL;     // 32768
    const size_t NQ = (size_t)BB * QL;     // 4096

    float* xgA  = alloc(2 * NC * GATES);   // gate preacts, reused per layer
    float* gbuf = alloc(NC * 1024);        // g  (xgQ aliases its head: dead before g written)
    float* xgQ  = gbuf;
    float* co   = alloc(NC * 256);
    float* qo   = alloc(NQ * 256);
    float* sbuf = alloc(NC * QL);          // s, then a (in place)
    float* cw   = alloc(NC);
    float* qw   = alloc(NQ);
    float* smax = alloc(NC);
    float* bw   = alloc(NC);
    float* q2c  = alloc((size_t)BB * 256);
    float* mmid = alloc(NC * 256);
    float* mbuf = alloc(NC * 256);
    float* m2o  = alloc(NC * 256);
    float* lp1  = alloc(NC);
    float* lp2  = alloc(NC);
    // bf16 weight planes: [3][1024][Ksp]
    ushort* WqP  = allocU((size_t)3 * 1024 * 320);
    ushort* WpP  = allocU((size_t)3 * 1024 * 320);
    ushort* Wm1P = allocU((size_t)3 * 1024 * 1024);
    ushort* Wm2P = allocU((size_t)3 * 1024 * 256);
    ushort* WoP  = allocU((size_t)3 * 1024 * 256);
    (void)ws_size; (void)in_sizes; (void)n_in; (void)out_size;

    // ---- weight splits ----
    splitW_k<<<dim3(1024 * 80 / 256), 256, 0, stream>>>(qenc_Wih, WqP, 300, 320);
    splitW_k<<<dim3(1024 * 80 / 256), 256, 0, stream>>>(penc_Wih, WpP, 300, 320);
    splitW_k<<<dim3(1024 * 256 / 256), 256, 0, stream>>>(m1_Wih, Wm1P, 1024, 1024);
    splitW_k<<<dim3(1024 * 64 / 256), 256, 0, stream>>>(m2_Wih, Wm2P, 256, 256);
    splitW_k<<<dim3(1024 * 64 / 256), 256, 0, stream>>>(out_Wih, WoP, 256, 256);

    // ---- encoders (scans fused across P/Q: 256 blocks) ----
    gemm_bf16x3<<<dim3((int)(NQ / TM), 4, 2), 256, 0, stream>>>(emb, q, WqP, qenc_b, xgQ, (int)NQ, 300, 320);
    gemm_bf16x3<<<dim3((int)(NC / TM), 4, 2), 256, 0, stream>>>(emb, p, WpP, penc_b, xgA, (int)NC, 300, 320);
    lstm_scan2<<<dim3(BB, 2, 2), 512, 0, stream>>>(xgA, penc_Whh, co, CL,
                                                   xgQ, qenc_Whh, qo, QL);

    // ---- attention ----
    rowdot<<<dim3((int)(NC * 64 / 256)), 256, 0, stream>>>(co, att_wc, cw, (int)NC, 256);
    rowdot<<<dim3((int)(NQ * 64 / 256)), 256, 0, stream>>>(qo, att_wq, qw, (int)NQ, 256);
    att_s<<<dim3(BB, CL / 64), 256, 0, stream>>>(co, qo, cw, qw, att_wcq, att_b, sbuf);
    softmax_q<<<dim3((int)(NC * 64 / 256)), 256, 0, stream>>>(sbuf, smax);
    bw_k<<<dim3(BB), 512, 0, stream>>>(smax, bw);
    q2c_k<<<dim3(BB), 256, 0, stream>>>(bw, co, q2c);
    c2q_g<<<dim3(BB, CL / 64), 256, 0, stream>>>(sbuf, qo, co, q2c, gbuf);

    // ---- modeling layers ----
    gemm_bf16x3<<<dim3((int)(NC / TM), 4, 2), 256, 0, stream>>>(gbuf, nullptr, Wm1P, m1_b, xgA, (int)NC, 1024, 1024);
    lstm_scan2<<<dim3(BB, 2, 1), 512, 0, stream>>>(xgA, m1_Whh, mmid, CL,
                                                   xgA, m1_Whh, mmid, CL);
    gemm_bf16x3<<<dim3((int)(NC / TM), 4, 2), 256, 0, stream>>>(mmid, nullptr, Wm2P, m2_b, xgA, (int)NC, 256, 256);
    lstm_scan2<<<dim3(BB, 2, 1), 512, 0, stream>>>(xgA, m2_Whh, mbuf, CL,
                                                   xgA, m2_Whh, mbuf, CL);
    gemm_bf16x3<<<dim3((int)(NC / TM), 4, 2), 256, 0, stream>>>(mbuf, nullptr, WoP, out_b, xgA, (int)NC, 256, 256);
    lstm_scan2<<<dim3(BB, 2, 1), 512, 0, stream>>>(xgA, out_Whh, m2o, CL,
                                                   xgA, out_Whh, m2o, CL);

    // ---- output ----
    logits_k<<<dim3((int)(NC * 64 / 256)), 256, 0, stream>>>(gbuf, mbuf, m2o,
        p1_wg, p1_wm, p1_b, p2_wg, p2_wm, p2_b, lp1, lp2);
    masked_softmax<<<dim3(BB, 2), 512, 0, stream>>>(lp1, lp2, p, (float*)d_out);
}